// Round 14
// baseline (165.253 us; speedup 1.0000x reference)
//
#include <hip/hip_runtime.h>
#include <hip/hip_fp16.h>

#define NN 20000
#define EE 320000
#define GG 50
#define IN_ 64
#define H1_ 10
#define D1_ 64
#define D2_ 128
#define F1 640   /* H1_*D1_ */
#define NEG 0.2f
#define CAP 128  /* bucket capacity per dst (P(deg>128) ~ 0 for Poisson(16)) */

static inline int cdiv(long long a, int b){ return (int)((a + b - 1) / b); }

__device__ inline float lrelu(float x){ return x > 0.f ? x : NEG * x; }

// acc += (f16 lo/hi of packed) * a   — fp32 accumulate, single VOP3P op
__device__ inline void fma_mix_lo(float& acc, float packed, float a){
  asm("v_fma_mix_f32 %0, %1, %2, %0 op_sel_hi:[1,0,0]"
      : "+v"(acc) : "v"(packed), "v"(a));
}
__device__ inline void fma_mix_hi(float& acc, float packed, float a){
  asm("v_fma_mix_f32 %0, %1, %2, %0 op_sel:[1,0,0] op_sel_hi:[1,0,0]"
      : "+v"(acc) : "v"(packed), "v"(a));
}

// ---------------- fused: bucket-scatter CSR (blocks 0..1249) + GEMM1 (rest) ----------------
// gemm1: B tile staged fp16, consumed via v_fma_mix (fp32 accumulate).
__global__ __launch_bounds__(256) void fused1(
    const int* __restrict__ src, const int* __restrict__ dst,
    int* __restrict__ cur, int* __restrict__ ssrc,
    const float* __restrict__ feat, const float* __restrict__ W1,
    const float* __restrict__ al1, const float* __restrict__ ar1,
    __half* __restrict__ ft1h, float* __restrict__ elT, float* __restrict__ erT){
  __shared__ float AsT[64][68];     // [k][r] fp32  17.4KB
  __shared__ __half Bsh[64][68];    // [k][c] fp16   8.7KB
  int b = blockIdx.x;
  if(b < 1250){
    int e = b * 256 + threadIdx.x;   // EE == 1250*256 exactly
    int d = dst[e];
    int pos = atomicAdd(&cur[d], 1);
    if(pos < CAP) ssrc[(d << 7) + pos] = src[e];
    return;
  }
  int b2 = b - 1250;
  int h = b2 % H1_;
  int n0 = (b2 / H1_) * 64;
  int tid = threadIdx.x;
  #pragma unroll
  for(int l = 0; l < 4; l++){
    int idx = tid + l * 256;
    int r = idx >> 4, c4 = (idx & 15) << 2;
    float4 v = make_float4(0.f,0.f,0.f,0.f);
    if(n0 + r < NN) v = *(const float4*)&feat[(size_t)(n0 + r) * IN_ + c4];
    AsT[c4+0][r] = v.x; AsT[c4+1][r] = v.y; AsT[c4+2][r] = v.z; AsT[c4+3][r] = v.w;
    float4 w = *(const float4*)&W1[(size_t)(idx >> 4) * F1 + h * 64 + c4];
    union { __half2 h2[2]; float2 f2; } u;
    u.h2[0] = __floats2half2_rn(w.x, w.y);
    u.h2[1] = __floats2half2_rn(w.z, w.w);
    *(float2*)&Bsh[idx >> 4][c4] = u.f2;
  }
  __syncthreads();
  int tr = tid >> 4, tc = tid & 15;
  float acc[4][4];
  #pragma unroll
  for(int i = 0; i < 4; i++)
    #pragma unroll
    for(int j = 0; j < 4; j++) acc[i][j] = 0.f;
  #pragma unroll 8
  for(int k = 0; k < 64; k++){
    float4 a4 = *(const float4*)&AsT[k][tr << 2];
    float2 b2v = *(const float2*)&Bsh[k][tc << 2];
    float av[4] = {a4.x, a4.y, a4.z, a4.w};
    #pragma unroll
    for(int i = 0; i < 4; i++){
      fma_mix_lo(acc[i][0], b2v.x, av[i]);
      fma_mix_hi(acc[i][1], b2v.x, av[i]);
      fma_mix_lo(acc[i][2], b2v.y, av[i]);
      fma_mix_hi(acc[i][3], b2v.y, av[i]);
    }
  }
  float al4[4], ar4[4];
  #pragma unroll
  for(int j = 0; j < 4; j++){
    al4[j] = al1[h * 64 + (tc << 2) + j];
    ar4[j] = ar1[h * 64 + (tc << 2) + j];
  }
  #pragma unroll
  for(int i = 0; i < 4; i++){
    int row = n0 + (tr << 2) + i;
    bool ok = row < NN;
    if(ok){
      union { __half2 h2[2]; float2 f2; } u;
      u.h2[0] = __floats2half2_rn(acc[i][0], acc[i][1]);
      u.h2[1] = __floats2half2_rn(acc[i][2], acc[i][3]);
      *(float2*)&ft1h[((size_t)h * NN + row) * 64 + (tc << 2)] = u.f2;
    }
    float e1 = acc[i][0]*al4[0] + acc[i][1]*al4[1] + acc[i][2]*al4[2] + acc[i][3]*al4[3];
    float e2 = acc[i][0]*ar4[0] + acc[i][1]*ar4[1] + acc[i][2]*ar4[2] + acc[i][3]*ar4[3];
    #pragma unroll
    for(int off = 1; off < 16; off <<= 1){
      e1 += __shfl_xor(e1, off, 64);
      e2 += __shfl_xor(e2, off, 64);
    }
    if(tc == 0 && ok){
      elT[(size_t)h * NN + row] = e1;
      erT[(size_t)h * NN + row] = e2;
    }
  }
}

// ---------------- layer-1 attn+agg: 2 dn per 32-lane half, A/B-interleaved agg ----------------
__global__ __launch_bounds__(256) void l1_head(
    const int* __restrict__ cur, const int* __restrict__ ssrc,
    const float* __restrict__ elT, const float* __restrict__ erT,
    const __half* __restrict__ ft1h, const float* __restrict__ b1,
    __half* __restrict__ out1h){
  __shared__ int2 pairs[4][2][2][32];
  int b = blockIdx.x;
  int xcd = b & 7, slot = b >> 3;
  int h, blk;
  if(slot < 1250){ h = xcd; blk = slot; }
  else {
    int s = slot - 1250; h = 8 + (xcd >> 2); blk = (xcd & 3) * 313 + s;
    if(blk >= 1250) return;
  }
  int wave = threadIdx.x >> 6, lane = threadIdx.x & 63;
  int half = lane >> 5, l32 = lane & 31;
  int eg = l32 >> 4, dg = l32 & 15;
  int dnA = blk * 16 + wave * 4 + half * 2;
  int dnB = dnA + 1;
  int degA = min(cur[dnA], CAP), degB = min(cur[dnB], CAP);
  int baseA = dnA << 7, baseB = dnB << 7;
  float4 accA = make_float4(0.f,0.f,0.f,0.f);
  float4 accB = make_float4(0.f,0.f,0.f,0.f);
  const char* fbase = (const char*)(ft1h + (size_t)h * NN * 64) + (dg << 3);
  const float* elh = elT + (size_t)h * NN;
  float erA = erT[(size_t)h * NN + dnA];
  float erB = erT[(size_t)h * NN + dnB];
  int2* wpA = pairs[wave][half][0];
  int2* wpB = pairs[wave][half][1];

  if(__any(degA > 32 || degB > 32)){
    // chunked fallback (rare)
    #pragma unroll
    for(int which = 0; which < 2; which++){
      int base = which ? baseB : baseA;
      int deg  = which ? degB : degA;
      float er_h = which ? erB : erA;
      float4* accp = which ? &accB : &accA;
      int2* wp = which ? wpB : wpA;
      float sm = 0.f;
      for(int i = l32; i < deg; i += 32)
        sm += __expf(lrelu(elh[ssrc[base + i]] + er_h));
      #pragma unroll
      for(int o = 1; o < 32; o <<= 1) sm += __shfl_xor(sm, o, 64);
      float inv = deg > 0 ? 1.f / sm : 0.f;
      for(int c = 0; c < deg; c += 32){
        int m = deg - c; if(m > 32) m = 32;
        if(l32 < m){
          int sn = ssrc[base + c + l32];
          wp[l32] = make_int2(__float_as_int(__expf(lrelu(elh[sn] + er_h)) * inv), sn << 7);
        }
        for(int i = eg; i < m; i += 2){
          int2 pr = wp[i];
          float a_i = __int_as_float(pr.x);
          float2 raw = *(const float2*)(fbase + pr.y);
          fma_mix_lo(accp->x, raw.x, a_i); fma_mix_hi(accp->y, raw.x, a_i);
          fma_mix_lo(accp->z, raw.y, a_i); fma_mix_hi(accp->w, raw.y, a_i);
        }
      }
    }
  } else {
    int snA = 0, snB = 0;
    if(l32 < degA) snA = ssrc[baseA + l32];
    if(l32 < degB) snB = ssrc[baseB + l32];
    float pA = 0.f, pB = 0.f;
    if(l32 < degA) pA = __expf(lrelu(elh[snA] + erA));
    if(l32 < degB) pB = __expf(lrelu(elh[snB] + erB));
    float smA = pA, smB = pB;
    #pragma unroll
    for(int o = 1; o < 32; o <<= 1){
      smA += __shfl_xor(smA, o, 64);
      smB += __shfl_xor(smB, o, 64);
    }
    float invA = degA > 0 ? 1.f / smA : 0.f;
    float invB = degB > 0 ? 1.f / smB : 0.f;
    wpA[l32] = l32 < degA ? make_int2(__float_as_int(pA * invA), snA << 7)
                          : make_int2(0, 0);
    wpB[l32] = l32 < degB ? make_int2(__float_as_int(pB * invB), snB << 7)
                          : make_int2(0, 0);
    int maxd = max(degA, degB);
    int i = eg;
    for(; i + 2 < maxd; i += 4){
      int2 a0 = wpA[i], a1 = wpA[i + 2];
      int2 b0 = wpB[i], b1 = wpB[i + 2];
      float2 ra0 = *(const float2*)(fbase + a0.y);
      float2 rb0 = *(const float2*)(fbase + b0.y);
      float2 ra1 = *(const float2*)(fbase + a1.y);
      float2 rb1 = *(const float2*)(fbase + b1.y);
      float aa0 = __int_as_float(a0.x), aa1 = __int_as_float(a1.x);
      float ab0 = __int_as_float(b0.x), ab1 = __int_as_float(b1.x);
      fma_mix_lo(accA.x, ra0.x, aa0); fma_mix_hi(accA.y, ra0.x, aa0);
      fma_mix_lo(accA.z, ra0.y, aa0); fma_mix_hi(accA.w, ra0.y, aa0);
      fma_mix_lo(accB.x, rb0.x, ab0); fma_mix_hi(accB.y, rb0.x, ab0);
      fma_mix_lo(accB.z, rb0.y, ab0); fma_mix_hi(accB.w, rb0.y, ab0);
      fma_mix_lo(accA.x, ra1.x, aa1); fma_mix_hi(accA.y, ra1.x, aa1);
      fma_mix_lo(accA.z, ra1.y, aa1); fma_mix_hi(accA.w, ra1.y, aa1);
      fma_mix_lo(accB.x, rb1.x, ab1); fma_mix_hi(accB.y, rb1.x, ab1);
      fma_mix_lo(accB.z, rb1.y, ab1); fma_mix_hi(accB.w, rb1.y, ab1);
    }
    if(i < maxd){
      int2 a0 = wpA[i], b0 = wpB[i];
      float2 ra0 = *(const float2*)(fbase + a0.y);
      float2 rb0 = *(const float2*)(fbase + b0.y);
      float aa0 = __int_as_float(a0.x), ab0 = __int_as_float(b0.x);
      fma_mix_lo(accA.x, ra0.x, aa0); fma_mix_hi(accA.y, ra0.x, aa0);
      fma_mix_lo(accA.z, ra0.y, aa0); fma_mix_hi(accA.w, ra0.y, aa0);
      fma_mix_lo(accB.x, rb0.x, ab0); fma_mix_hi(accB.y, rb0.x, ab0);
      fma_mix_lo(accB.z, rb0.y, ab0); fma_mix_hi(accB.w, rb0.y, ab0);
    }
  }
  accA.x += __shfl_xor(accA.x, 16, 64); accB.x += __shfl_xor(accB.x, 16, 64);
  accA.y += __shfl_xor(accA.y, 16, 64); accB.y += __shfl_xor(accB.y, 16, 64);
  accA.z += __shfl_xor(accA.z, 16, 64); accB.z += __shfl_xor(accB.z, 16, 64);
  accA.w += __shfl_xor(accA.w, 16, 64); accB.w += __shfl_xor(accB.w, 16, 64);
  if(eg == 0){
    int d = dg << 2;
    const float* bp = &b1[h * 64 + d];
    float b0 = bp[0], b1v = bp[1], b2v = bp[2], b3 = bp[3];
    union { __half2 h2[2]; float2 f2; } u;
    u.h2[0] = __floats2half2_rn(fmaxf(accA.x + b0, 0.f), fmaxf(accA.y + b1v, 0.f));
    u.h2[1] = __floats2half2_rn(fmaxf(accA.z + b2v, 0.f), fmaxf(accA.w + b3, 0.f));
    *(float2*)&out1h[(size_t)dnA * F1 + h * 64 + d] = u.f2;
    u.h2[0] = __floats2half2_rn(fmaxf(accB.x + b0, 0.f), fmaxf(accB.y + b1v, 0.f));
    u.h2[1] = __floats2half2_rn(fmaxf(accB.z + b2v, 0.f), fmaxf(accB.w + b3, 0.f));
    *(float2*)&out1h[(size_t)dnB * F1 + h * 64 + d] = u.f2;
  }
}

// ---------------- GEMM2: A = head-sum(out1h) on the fly; B fp16 via fma_mix ----------------
__global__ __launch_bounds__(256) void gemm2(
    const __half* __restrict__ out1h, const float* __restrict__ W2,
    const float* __restrict__ al2, const float* __restrict__ ar2,
    __half* __restrict__ ft2h, float* __restrict__ el, float* __restrict__ er){
  __shared__ float AsT[64][36];     // [k][r] fp32  9.2KB
  __shared__ __half Bsh[64][132];   // [k][c] fp16 16.9KB
  int n0 = blockIdx.x * 32;
  int tid = threadIdx.x;
  #pragma unroll
  for(int l = 0; l < 2; l++){
    int idx = tid + l * 256;
    int r = idx >> 4, c4 = (idx & 15) << 2;
    float4 sv = make_float4(0.f,0.f,0.f,0.f);
    if(n0 + r < NN){
      const __half* rp = &out1h[(size_t)(n0 + r) * F1 + c4];
      #pragma unroll
      for(int hh = 0; hh < H1_; hh++){
        float2 raw = *(const float2*)(rp + hh * 64);
        const __half2* hp = (const __half2*)&raw;
        float2 f0 = __half22float2(hp[0]);
        float2 f1 = __half22float2(hp[1]);
        sv.x += f0.x; sv.y += f0.y; sv.z += f1.x; sv.w += f1.y;
      }
    }
    AsT[c4+0][r] = sv.x; AsT[c4+1][r] = sv.y; AsT[c4+2][r] = sv.z; AsT[c4+3][r] = sv.w;
  }
  #pragma unroll
  for(int l = 0; l < 8; l++){
    int idx = tid + l * 256;
    int k = idx >> 5, c4 = (idx & 31) << 2;
    float4 w = *(const float4*)&W2[(size_t)k * D2_ + c4];
    union { __half2 h2[2]; float2 f2; } u;
    u.h2[0] = __floats2half2_rn(w.x, w.y);
    u.h2[1] = __floats2half2_rn(w.z, w.w);
    *(float2*)&Bsh[k][c4] = u.f2;
  }
  __syncthreads();
  int tr = tid >> 5, tc = tid & 31;
  float acc[4][4];
  #pragma unroll
  for(int i = 0; i < 4; i++)
    #pragma unroll
    for(int j = 0; j < 4; j++) acc[i][j] = 0.f;
  #pragma unroll 8
  for(int k = 0; k < 64; k++){
    float4 a4 = *(const float4*)&AsT[k][tr << 2];
    float2 b2v = *(const float2*)&Bsh[k][tc << 2];
    float av[4] = {a4.x, a4.y, a4.z, a4.w};
    #pragma unroll
    for(int i = 0; i < 4; i++){
      fma_mix_lo(acc[i][0], b2v.x, av[i]);
      fma_mix_hi(acc[i][1], b2v.x, av[i]);
      fma_mix_lo(acc[i][2], b2v.y, av[i]);
      fma_mix_hi(acc[i][3], b2v.y, av[i]);
    }
  }
  float al4[4], ar4[4];
  #pragma unroll
  for(int j = 0; j < 4; j++){
    al4[j] = al2[(tc << 2) + j];
    ar4[j] = ar2[(tc << 2) + j];
  }
  int col = tc << 2;
  int half = col >> 6, c64 = col & 63;
  #pragma unroll
  for(int i = 0; i < 4; i++){
    int row = n0 + (tr << 2) + i;
    bool ok = row < NN;
    if(ok){
      union { __half2 h2[2]; float2 f2; } u;
      u.h2[0] = __floats2half2_rn(acc[i][0], acc[i][1]);
      u.h2[1] = __floats2half2_rn(acc[i][2], acc[i][3]);
      *(float2*)&ft2h[((size_t)half * NN + row) * 64 + c64] = u.f2;
    }
    float e1 = acc[i][0]*al4[0] + acc[i][1]*al4[1] + acc[i][2]*al4[2] + acc[i][3]*al4[3];
    float e2 = acc[i][0]*ar4[0] + acc[i][1]*ar4[1] + acc[i][2]*ar4[2] + acc[i][3]*ar4[3];
    #pragma unroll
    for(int off = 1; off < 32; off <<= 1){
      e1 += __shfl_xor(e1, off, 64);
      e2 += __shfl_xor(e2, off, 64);
    }
    if(tc == 0 && ok){ el[row] = e1; er[row] = e2; }
  }
}

// ---------------- layer-2 attn+agg: 2 dn per half, A/B-interleaved; XCD-pinned d-half ----------------
__global__ __launch_bounds__(256) void l2_head(
    const int* __restrict__ cur, const int* __restrict__ ssrc,
    const float* __restrict__ el, const float* __restrict__ er,
    const __half* __restrict__ ft2h, const float* __restrict__ b2,
    float* __restrict__ h2v){
  __shared__ int2 pairs[4][2][2][32];
  int b = blockIdx.x;
  int xcd = b & 7, slot = b >> 3;
  int halfd = xcd >> 2;
  int blk = (xcd & 3) * 313 + slot;
  if(blk >= 1250) return;
  int wave = threadIdx.x >> 6, lane = threadIdx.x & 63;
  int half = lane >> 5, l32 = lane & 31;
  int eg = l32 >> 4, dg = l32 & 15;
  int dnA = blk * 16 + wave * 4 + half * 2;
  int dnB = dnA + 1;
  int degA = min(cur[dnA], CAP), degB = min(cur[dnB], CAP);
  int baseA = dnA << 7, baseB = dnB << 7;
  float4 accA = make_float4(0.f,0.f,0.f,0.f);
  float4 accB = make_float4(0.f,0.f,0.f,0.f);
  const char* fbase = (const char*)(ft2h + (size_t)halfd * NN * 64) + (dg << 3);
  float erA = er[dnA], erB = er[dnB];
  int2* wpA = pairs[wave][half][0];
  int2* wpB = pairs[wave][half][1];

  if(__any(degA > 32 || degB > 32)){
    #pragma unroll
    for(int which = 0; which < 2; which++){
      int base = which ? baseB : baseA;
      int deg  = which ? degB : degA;
      float er_d = which ? erB : erA;
      float4* accp = which ? &accB : &accA;
      int2* wp = which ? wpB : wpA;
      float sm = 0.f;
      for(int i = l32; i < deg; i += 32)
        sm += __expf(lrelu(el[ssrc[base + i]] + er_d));
      #pragma unroll
      for(int o = 1; o < 32; o <<= 1) sm += __shfl_xor(sm, o, 64);
      float inv = deg > 0 ? 1.f / sm : 0.f;
      for(int c = 0; c < deg; c += 32){
        int m = deg - c; if(m > 32) m = 32;
        if(l32 < m){
          int sn = ssrc[base + c + l32];
          wp[l32] = make_int2(__float_as_int(__expf(lrelu(el[sn] + er_d)) * inv), sn << 7);
        }
        for(int i = eg; i < m; i += 2){
          int2 pr = wp[i];
          float a_i = __int_as_float(pr.x);
          float2 raw = *(const float2*)(fbase + pr.y);
          fma_mix_lo(accp->x, raw.x, a_i); fma_mix_hi(accp->y, raw.x, a_i);
          fma_mix_lo(accp->z, raw.y, a_i); fma_mix_hi(accp->w, raw.y, a_i);
        }
      }
    }
  } else {
    int snA = 0, snB = 0;
    if(l32 < degA) snA = ssrc[baseA + l32];
    if(l32 < degB) snB = ssrc[baseB + l32];
    float pA = 0.f, pB = 0.f;
    if(l32 < degA) pA = __expf(lrelu(el[snA] + erA));
    if(l32 < degB) pB = __expf(lrelu(el[snB] + erB));
    float smA = pA, smB = pB;
    #pragma unroll
    for(int o = 1; o < 32; o <<= 1){
      smA += __shfl_xor(smA, o, 64);
      smB += __shfl_xor(smB, o, 64);
    }
    float invA = degA > 0 ? 1.f / smA : 0.f;
    float invB = degB > 0 ? 1.f / smB : 0.f;
    wpA[l32] = l32 < degA ? make_int2(__float_as_int(pA * invA), snA << 7)
                          : make_int2(0, 0);
    wpB[l32] = l32 < degB ? make_int2(__float_as_int(pB * invB), snB << 7)
                          : make_int2(0, 0);
    int maxd = max(degA, degB);
    int i = eg;
    for(; i + 2 < maxd; i += 4){
      int2 a0 = wpA[i], a1 = wpA[i + 2];
      int2 b0 = wpB[i], b1 = wpB[i + 2];
      float2 ra0 = *(const float2*)(fbase + a0.y);
      float2 rb0 = *(const float2*)(fbase + b0.y);
      float2 ra1 = *(const float2*)(fbase + a1.y);
      float2 rb1 = *(const float2*)(fbase + b1.y);
      float aa0 = __int_as_float(a0.x), aa1 = __int_as_float(a1.x);
      float ab0 = __int_as_float(b0.x), ab1 = __int_as_float(b1.x);
      fma_mix_lo(accA.x, ra0.x, aa0); fma_mix_hi(accA.y, ra0.x, aa0);
      fma_mix_lo(accA.z, ra0.y, aa0); fma_mix_hi(accA.w, ra0.y, aa0);
      fma_mix_lo(accB.x, rb0.x, ab0); fma_mix_hi(accB.y, rb0.x, ab0);
      fma_mix_lo(accB.z, rb0.y, ab0); fma_mix_hi(accB.w, rb0.y, ab0);
      fma_mix_lo(accA.x, ra1.x, aa1); fma_mix_hi(accA.y, ra1.x, aa1);
      fma_mix_lo(accA.z, ra1.y, aa1); fma_mix_hi(accA.w, ra1.y, aa1);
      fma_mix_lo(accB.x, rb1.x, ab1); fma_mix_hi(accB.y, rb1.x, ab1);
      fma_mix_lo(accB.z, rb1.y, ab1); fma_mix_hi(accB.w, rb1.y, ab1);
    }
    if(i < maxd){
      int2 a0 = wpA[i], b0 = wpB[i];
      float2 ra0 = *(const float2*)(fbase + a0.y);
      float2 rb0 = *(const float2*)(fbase + b0.y);
      float aa0 = __int_as_float(a0.x), ab0 = __int_as_float(b0.x);
      fma_mix_lo(accA.x, ra0.x, aa0); fma_mix_hi(accA.y, ra0.x, aa0);
      fma_mix_lo(accA.z, ra0.y, aa0); fma_mix_hi(accA.w, ra0.y, aa0);
      fma_mix_lo(accB.x, rb0.x, ab0); fma_mix_hi(accB.y, rb0.x, ab0);
      fma_mix_lo(accB.z, rb0.y, ab0); fma_mix_hi(accB.w, rb0.y, ab0);
    }
  }
  accA.x += __shfl_xor(accA.x, 16, 64); accB.x += __shfl_xor(accB.x, 16, 64);
  accA.y += __shfl_xor(accA.y, 16, 64); accB.y += __shfl_xor(accB.y, 16, 64);
  accA.z += __shfl_xor(accA.z, 16, 64); accB.z += __shfl_xor(accB.z, 16, 64);
  accA.w += __shfl_xor(accA.w, 16, 64); accB.w += __shfl_xor(accB.w, 16, 64);
  if(eg == 0){
    int doff = halfd * 64 + (dg << 2);
    const float* bp = &b2[doff];
    float b0 = bp[0], b1v = bp[1], b2v = bp[2], b3 = bp[3];
    float4 o;
    o.x = fmaxf(accA.x + b0, 0.f);
    o.y = fmaxf(accA.y + b1v, 0.f);
    o.z = fmaxf(accA.z + b2v, 0.f);
    o.w = fmaxf(accA.w + b3, 0.f);
    *(float4*)&h2v[(size_t)dnA * D2_ + doff] = o;
    o.x = fmaxf(accB.x + b0, 0.f);
    o.y = fmaxf(accB.y + b1v, 0.f);
    o.z = fmaxf(accB.z + b2v, 0.f);
    o.w = fmaxf(accB.w + b3, 0.f);
    *(float4*)&h2v[(size_t)dnB * D2_ + doff] = o;
  }
}

// ---------------- fused per-graph max + final MLP (graph_ids sorted) ----------------
__global__ __launch_bounds__(256) void readout(
    const float* __restrict__ h2v, const int* __restrict__ gid,
    const float* __restrict__ lw1, const float* __restrict__ lb1,
    const float* __restrict__ lw2, const float* __restrict__ lb2,
    float* __restrict__ out){
  __shared__ int sb[2];
  __shared__ float mx2[2][D2_];
  __shared__ float rv[D2_];
  __shared__ float t[D2_];
  int g = blockIdx.x, tid = threadIdx.x;
  int d = tid & 127, hh = tid >> 7;
  if(tid < 2){
    int tgt = g + tid;  // lower_bound(gid, tgt)
    int lo = 0, hi = NN;
    while(lo < hi){ int mid = (lo + hi) >> 1; if(gid[mid] < tgt) lo = mid + 1; else hi = mid; }
    sb[tid] = lo;
  }
  __syncthreads();
  int gs = sb[0], ge = sb[1];
  float m0 = 0.f, m1 = 0.f, m2 = 0.f, m3 = 0.f;
  int n = gs + hh;
  for(; n + 6 < ge; n += 8){
    m0 = fmaxf(m0, h2v[(size_t)(n + 0) * D2_ + d]);
    m1 = fmaxf(m1, h2v[(size_t)(n + 2) * D2_ + d]);
    m2 = fmaxf(m2, h2v[(size_t)(n + 4) * D2_ + d]);
    m3 = fmaxf(m3, h2v[(size_t)(n + 6) * D2_ + d]);
  }
  for(; n < ge; n += 2) m0 = fmaxf(m0, h2v[(size_t)n * D2_ + d]);
  mx2[hh][d] = fmaxf(fmaxf(m0, m1), fmaxf(m2, m3));
  __syncthreads();
  if(tid < D2_) rv[d] = fmaxf(mx2[0][d], mx2[1][d]);
  __syncthreads();
  if(tid < D2_){
    float acc = lb1[d];
    #pragma unroll 8
    for(int k = 0; k < D2_; k++) acc += rv[k] * lw1[k * D2_ + d];
    acc = acc > 0.f ? acc : 0.f;
    t[d] = acc * lw2[d];
  }
  __syncthreads();
  for(int off = 64; off > 0; off >>= 1){
    if(tid < off) t[tid] += t[tid + off];
    __syncthreads();
  }
  if(tid == 0){
    float v = t[0] + lb2[0];
    out[g] = v > 0.f ? v : 0.f;
  }
}

extern "C" void kernel_launch(void* const* d_in, const int* in_sizes, int n_in,
                              void* d_out, int out_size, void* d_ws, size_t ws_size,
                              hipStream_t stream) {
  const float* feat = (const float*)d_in[0];
  const int*   src  = (const int*)d_in[1];
  const int*   dst  = (const int*)d_in[2];
  const int*   gid  = (const int*)d_in[3];
  const float* W1   = (const float*)d_in[4];
  const float* al1  = (const float*)d_in[5];
  const float* ar1  = (const float*)d_in[6];
  const float* b1   = (const float*)d_in[7];
  const float* W2   = (const float*)d_in[8];
  const float* al2  = (const float*)d_in[9];
  const float* ar2  = (const float*)d_in[10];
  const float* b2   = (const float*)d_in[11];
  const float* lw1  = (const float*)d_in[12];
  const float* lb1  = (const float*)d_in[13];
  const float* lw2  = (const float*)d_in[14];
  const float* lb2  = (const float*)d_in[15];
  float* out = (float*)d_out;

  float* ws = (float*)d_ws;
  size_t o = 0;
  __half* ft1h = (__half*)(ws + o); o += (size_t)NN * F1 / 2;   // 25.6MB
  __half* out1h = (__half*)(ws + o); o += (size_t)NN * F1 / 2;  // 25.6MB
  __half* ft2h = (__half*)(ws + o); o += (size_t)NN * D2_ / 2;  // 5.12MB
  float* h2v  = ws + o; o += (size_t)NN * D2_;                  // 10.24MB
  float* el1  = ws + o; o += (size_t)NN * H1_;
  float* er1  = ws + o; o += (size_t)NN * H1_;
  float* el2  = ws + o; o += NN;
  float* er2  = ws + o; o += NN;
  int* cur    = (int*)(ws + o); o += NN;
  int* ssrc   = (int*)(ws + o); o += (size_t)NN * CAP;          // 10.24MB

  // deg counters -> 0
  hipMemsetAsync(cur, 0, (size_t)NN * 4, stream);
  // fused: bucket scatter (1250 blocks) + gemm1 (3130 blocks)
  fused1<<<1250 + H1_ * cdiv(NN, 64), 256, 0, stream>>>(
      src, dst, cur, ssrc, feat, W1, al1, ar1, ft1h, el1, er1);
  // layer-1 attn+agg
  l1_head<<<8 * (1250 + 313), 256, 0, stream>>>(cur, ssrc, el1, er1, ft1h, b1, out1h);
  // layer 2 (head-sum fused into gemm2 A-load)
  gemm2<<<cdiv(NN, 32), 256, 0, stream>>>(out1h, W2, al2, ar2, ft2h, el2, er2);
  l2_head<<<8 * 313, 256, 0, stream>>>(cur, ssrc, el2, er2, ft2h, b2, h2v);
  // fused readout + MLP
  readout<<<GG, 256, 0, stream>>>(h2v, gid, lw1, lb1, lw2, lb2, out);
}

// Round 15
// 148.999 us; speedup vs baseline: 1.1091x; 1.1091x over previous
//
#include <hip/hip_runtime.h>
#include <hip/hip_fp16.h>

#define NN 20000
#define EE 320000
#define GG 50
#define IN_ 64
#define H1_ 10
#define D1_ 64
#define D2_ 128
#define F1 640   /* H1_*D1_ */
#define NEG 0.2f
#define CAP 128  /* bucket capacity per dst */

static inline int cdiv(long long a, int b){ return (int)((a + b - 1) / b); }

typedef _Float16 half8 __attribute__((ext_vector_type(8)));
typedef float f32x4 __attribute__((ext_vector_type(4)));

__device__ inline float lrelu(float x){ return x > 0.f ? x : NEG * x; }

// acc += (f16 lo/hi of packed) * a   — fp32 accumulate, single VOP3P op
__device__ inline void fma_mix_lo(float& acc, float packed, float a){
  asm("v_fma_mix_f32 %0, %1, %2, %0 op_sel_hi:[1,0,0]"
      : "+v"(acc) : "v"(packed), "v"(a));
}
__device__ inline void fma_mix_hi(float& acc, float packed, float a){
  asm("v_fma_mix_f32 %0, %1, %2, %0 op_sel:[1,0,0] op_sel_hi:[1,0,0]"
      : "+v"(acc) : "v"(packed), "v"(a));
}

// ---------------- prep: feat->fp16, W1^T fp16, zero cur ----------------
__global__ __launch_bounds__(256) void prep(
    const float* __restrict__ feat, const float* __restrict__ W1,
    _Float16* __restrict__ featH, _Float16* __restrict__ W1T,
    int* __restrict__ cur){
  int b = blockIdx.x, t = threadIdx.x;
  if(b < 1250){
    int idx = b * 1024 + t * 4;          // 1250*1024 == NN*IN_ exactly
    float4 v = *(const float4*)&feat[idx];
    _Float16 h4[4] = {(_Float16)v.x, (_Float16)v.y, (_Float16)v.z, (_Float16)v.w};
    *(float2*)&featH[idx] = *(float2*)h4;
    if(t < 16) cur[b * 16 + t] = 0;      // 1250*16 == NN
  } else {
    int idx = (b - 1250) * 1024 + t * 4; // 40*1024 == F1*IN_ exactly
    int c = idx >> 6, k0 = idx & 63;
    _Float16 h4[4];
    #pragma unroll
    for(int j = 0; j < 4; j++) h4[j] = (_Float16)W1[(size_t)(k0 + j) * F1 + c];
    *(float2*)&W1T[idx] = *(float2*)h4;
  }
}

// ---------------- fused: bucket-scatter (blocks 0..1249) + MFMA GEMM1 ----------------
// gemm block: 64 rows x 1 head; wave = 16 rows; 4 tiles x 2 K-frags mfma.
__global__ __launch_bounds__(256) void fused1(
    const int* __restrict__ src, const int* __restrict__ dst,
    int* __restrict__ cur, int* __restrict__ ssrc,
    const _Float16* __restrict__ featH, const _Float16* __restrict__ W1T,
    const float* __restrict__ al1, const float* __restrict__ ar1,
    _Float16* __restrict__ ft1h, float* __restrict__ elT, float* __restrict__ erT){
  __shared__ _Float16 sC[4][16][72];
  int b = blockIdx.x;
  if(b < 1250){
    int e = b * 256 + threadIdx.x;       // EE == 1250*256 exactly
    int d = dst[e];
    int pos = atomicAdd(&cur[d], 1);
    if(pos < CAP) ssrc[(d << 7) + pos] = src[e];
    return;
  }
  int b2 = b - 1250;
  int h = b2 % H1_;
  int n0 = (b2 / H1_) * 64;
  int tid = threadIdx.x, w = tid >> 6, l = tid & 63;
  int lr = l & 15, lk = l >> 4;
  int r0 = n0 + w * 16;
  int row = r0 + lr;
  half8 a0 = {}, a1 = {};
  if(row < NN){
    a0 = *(const half8*)&featH[row * 64 + lk * 8];
    a1 = *(const half8*)&featH[row * 64 + 32 + lk * 8];
  }
  f32x4 acc[4];
  #pragma unroll
  for(int c0 = 0; c0 < 4; c0++) acc[c0] = (f32x4){0.f, 0.f, 0.f, 0.f};
  #pragma unroll
  for(int c0 = 0; c0 < 4; c0++){
    int col = h * 64 + c0 * 16 + lr;
    half8 b0 = *(const half8*)&W1T[col * 64 + lk * 8];
    half8 b1 = *(const half8*)&W1T[col * 64 + 32 + lk * 8];
    acc[c0] = __builtin_amdgcn_mfma_f32_16x16x32_f16(a0, b0, acc[c0], 0, 0, 0);
    acc[c0] = __builtin_amdgcn_mfma_f32_16x16x32_f16(a1, b1, acc[c0], 0, 0, 0);
  }
  // el/er: reduce acc over the 16 col-lanes
  float elp[4] = {0.f,0.f,0.f,0.f}, erp[4] = {0.f,0.f,0.f,0.f};
  #pragma unroll
  for(int c0 = 0; c0 < 4; c0++){
    float al = al1[h * 64 + c0 * 16 + lr];
    float ar = ar1[h * 64 + c0 * 16 + lr];
    #pragma unroll
    for(int j = 0; j < 4; j++){
      elp[j] += acc[c0][j] * al;
      erp[j] += acc[c0][j] * ar;
    }
  }
  #pragma unroll
  for(int off = 1; off < 16; off <<= 1){
    #pragma unroll
    for(int j = 0; j < 4; j++){
      elp[j] += __shfl_xor(elp[j], off, 64);
      erp[j] += __shfl_xor(erp[j], off, 64);
    }
  }
  if(lr == 0){
    #pragma unroll
    for(int j = 0; j < 4; j++){
      int rj = r0 + lk * 4 + j;
      if(rj < NN){
        elT[(size_t)h * NN + rj] = elp[j];
        erT[(size_t)h * NN + rj] = erp[j];
      }
    }
  }
  // transpose C via per-wave LDS tile, then coalesced fp16 writes
  #pragma unroll
  for(int c0 = 0; c0 < 4; c0++)
    #pragma unroll
    for(int j = 0; j < 4; j++)
      sC[w][lk * 4 + j][c0 * 16 + lr] = (_Float16)acc[c0][j];
  __syncthreads();
  #pragma unroll
  for(int it = 0; it < 2; it++){
    int idx = l + it * 64;
    int orow = idx >> 3, oc = (idx & 7) * 8;
    int grow = r0 + orow;
    if(grow < NN)
      *(float4*)&ft1h[((size_t)h * NN + grow) * 64 + oc] =
          *(const float4*)&sC[w][orow][oc];
  }
}

// ---------------- layer-1 attn+agg: 2 dn per 32-lane half, A/B-interleaved agg ----------------
__global__ __launch_bounds__(256) void l1_head(
    const int* __restrict__ cur, const int* __restrict__ ssrc,
    const float* __restrict__ elT, const float* __restrict__ erT,
    const __half* __restrict__ ft1h, const float* __restrict__ b1,
    __half* __restrict__ out1h){
  __shared__ int2 pairs[4][2][2][32];
  int b = blockIdx.x;
  int xcd = b & 7, slot = b >> 3;
  int h, blk;
  if(slot < 1250){ h = xcd; blk = slot; }
  else {
    int s = slot - 1250; h = 8 + (xcd >> 2); blk = (xcd & 3) * 313 + s;
    if(blk >= 1250) return;
  }
  int wave = threadIdx.x >> 6, lane = threadIdx.x & 63;
  int half = lane >> 5, l32 = lane & 31;
  int eg = l32 >> 4, dg = l32 & 15;
  int dnA = blk * 16 + wave * 4 + half * 2;
  int dnB = dnA + 1;
  int degA = min(cur[dnA], CAP), degB = min(cur[dnB], CAP);
  int baseA = dnA << 7, baseB = dnB << 7;
  float4 accA = make_float4(0.f,0.f,0.f,0.f);
  float4 accB = make_float4(0.f,0.f,0.f,0.f);
  const char* fbase = (const char*)(ft1h + (size_t)h * NN * 64) + (dg << 3);
  const float* elh = elT + (size_t)h * NN;
  float erA = erT[(size_t)h * NN + dnA];
  float erB = erT[(size_t)h * NN + dnB];
  int2* wpA = pairs[wave][half][0];
  int2* wpB = pairs[wave][half][1];

  if(__any(degA > 32 || degB > 32)){
    #pragma unroll
    for(int which = 0; which < 2; which++){
      int base = which ? baseB : baseA;
      int deg  = which ? degB : degA;
      float er_h = which ? erB : erA;
      float4* accp = which ? &accB : &accA;
      int2* wp = which ? wpB : wpA;
      float sm = 0.f;
      for(int i = l32; i < deg; i += 32)
        sm += __expf(lrelu(elh[ssrc[base + i]] + er_h));
      #pragma unroll
      for(int o = 1; o < 32; o <<= 1) sm += __shfl_xor(sm, o, 64);
      float inv = deg > 0 ? 1.f / sm : 0.f;
      for(int c = 0; c < deg; c += 32){
        int m = deg - c; if(m > 32) m = 32;
        if(l32 < m){
          int sn = ssrc[base + c + l32];
          wp[l32] = make_int2(__float_as_int(__expf(lrelu(elh[sn] + er_h)) * inv), sn << 7);
        }
        for(int i = eg; i < m; i += 2){
          int2 pr = wp[i];
          float a_i = __int_as_float(pr.x);
          float2 raw = *(const float2*)(fbase + pr.y);
          fma_mix_lo(accp->x, raw.x, a_i); fma_mix_hi(accp->y, raw.x, a_i);
          fma_mix_lo(accp->z, raw.y, a_i); fma_mix_hi(accp->w, raw.y, a_i);
        }
      }
    }
  } else {
    int snA = 0, snB = 0;
    if(l32 < degA) snA = ssrc[baseA + l32];
    if(l32 < degB) snB = ssrc[baseB + l32];
    float pA = 0.f, pB = 0.f;
    if(l32 < degA) pA = __expf(lrelu(elh[snA] + erA));
    if(l32 < degB) pB = __expf(lrelu(elh[snB] + erB));
    float smA = pA, smB = pB;
    #pragma unroll
    for(int o = 1; o < 32; o <<= 1){
      smA += __shfl_xor(smA, o, 64);
      smB += __shfl_xor(smB, o, 64);
    }
    float invA = degA > 0 ? 1.f / smA : 0.f;
    float invB = degB > 0 ? 1.f / smB : 0.f;
    wpA[l32] = l32 < degA ? make_int2(__float_as_int(pA * invA), snA << 7)
                          : make_int2(0, 0);
    wpB[l32] = l32 < degB ? make_int2(__float_as_int(pB * invB), snB << 7)
                          : make_int2(0, 0);
    int maxd = max(degA, degB);
    int i = eg;
    for(; i + 2 < maxd; i += 4){
      int2 a0 = wpA[i], a1 = wpA[i + 2];
      int2 b0 = wpB[i], b1 = wpB[i + 2];
      float2 ra0 = *(const float2*)(fbase + a0.y);
      float2 rb0 = *(const float2*)(fbase + b0.y);
      float2 ra1 = *(const float2*)(fbase + a1.y);
      float2 rb1 = *(const float2*)(fbase + b1.y);
      float aa0 = __int_as_float(a0.x), aa1 = __int_as_float(a1.x);
      float ab0 = __int_as_float(b0.x), ab1 = __int_as_float(b1.x);
      fma_mix_lo(accA.x, ra0.x, aa0); fma_mix_hi(accA.y, ra0.x, aa0);
      fma_mix_lo(accA.z, ra0.y, aa0); fma_mix_hi(accA.w, ra0.y, aa0);
      fma_mix_lo(accB.x, rb0.x, ab0); fma_mix_hi(accB.y, rb0.x, ab0);
      fma_mix_lo(accB.z, rb0.y, ab0); fma_mix_hi(accB.w, rb0.y, ab0);
      fma_mix_lo(accA.x, ra1.x, aa1); fma_mix_hi(accA.y, ra1.x, aa1);
      fma_mix_lo(accA.z, ra1.y, aa1); fma_mix_hi(accA.w, ra1.y, aa1);
      fma_mix_lo(accB.x, rb1.x, ab1); fma_mix_hi(accB.y, rb1.x, ab1);
      fma_mix_lo(accB.z, rb1.y, ab1); fma_mix_hi(accB.w, rb1.y, ab1);
    }
    if(i < maxd){
      int2 a0 = wpA[i], b0 = wpB[i];
      float2 ra0 = *(const float2*)(fbase + a0.y);
      float2 rb0 = *(const float2*)(fbase + b0.y);
      float aa0 = __int_as_float(a0.x), ab0 = __int_as_float(b0.x);
      fma_mix_lo(accA.x, ra0.x, aa0); fma_mix_hi(accA.y, ra0.x, aa0);
      fma_mix_lo(accA.z, ra0.y, aa0); fma_mix_hi(accA.w, ra0.y, aa0);
      fma_mix_lo(accB.x, rb0.x, ab0); fma_mix_hi(accB.y, rb0.x, ab0);
      fma_mix_lo(accB.z, rb0.y, ab0); fma_mix_hi(accB.w, rb0.y, ab0);
    }
  }
  accA.x += __shfl_xor(accA.x, 16, 64); accB.x += __shfl_xor(accB.x, 16, 64);
  accA.y += __shfl_xor(accA.y, 16, 64); accB.y += __shfl_xor(accB.y, 16, 64);
  accA.z += __shfl_xor(accA.z, 16, 64); accB.z += __shfl_xor(accB.z, 16, 64);
  accA.w += __shfl_xor(accA.w, 16, 64); accB.w += __shfl_xor(accB.w, 16, 64);
  if(eg == 0){
    int d = dg << 2;
    const float* bp = &b1[h * 64 + d];
    float b0 = bp[0], b1v = bp[1], b2v = bp[2], b3 = bp[3];
    union { __half2 h2[2]; float2 f2; } u;
    u.h2[0] = __floats2half2_rn(fmaxf(accA.x + b0, 0.f), fmaxf(accA.y + b1v, 0.f));
    u.h2[1] = __floats2half2_rn(fmaxf(accA.z + b2v, 0.f), fmaxf(accA.w + b3, 0.f));
    *(float2*)&out1h[(size_t)dnA * F1 + h * 64 + d] = u.f2;
    u.h2[0] = __floats2half2_rn(fmaxf(accB.x + b0, 0.f), fmaxf(accB.y + b1v, 0.f));
    u.h2[1] = __floats2half2_rn(fmaxf(accB.z + b2v, 0.f), fmaxf(accB.w + b3, 0.f));
    *(float2*)&out1h[(size_t)dnB * F1 + h * 64 + d] = u.f2;
  }
}

// ---------------- GEMM2: A = head-sum(out1h) on the fly; B fp16 via fma_mix ----------------
__global__ __launch_bounds__(256) void gemm2(
    const __half* __restrict__ out1h, const float* __restrict__ W2,
    const float* __restrict__ al2, const float* __restrict__ ar2,
    __half* __restrict__ ft2h, float* __restrict__ el, float* __restrict__ er){
  __shared__ float AsT[64][36];
  __shared__ __half Bsh[64][132];
  int n0 = blockIdx.x * 32;
  int tid = threadIdx.x;
  #pragma unroll
  for(int l = 0; l < 2; l++){
    int idx = tid + l * 256;
    int r = idx >> 4, c4 = (idx & 15) << 2;
    float4 sv = make_float4(0.f,0.f,0.f,0.f);
    if(n0 + r < NN){
      const __half* rp = &out1h[(size_t)(n0 + r) * F1 + c4];
      #pragma unroll
      for(int hh = 0; hh < H1_; hh++){
        float2 raw = *(const float2*)(rp + hh * 64);
        const __half2* hp = (const __half2*)&raw;
        float2 f0 = __half22float2(hp[0]);
        float2 f1 = __half22float2(hp[1]);
        sv.x += f0.x; sv.y += f0.y; sv.z += f1.x; sv.w += f1.y;
      }
    }
    AsT[c4+0][r] = sv.x; AsT[c4+1][r] = sv.y; AsT[c4+2][r] = sv.z; AsT[c4+3][r] = sv.w;
  }
  #pragma unroll
  for(int l = 0; l < 8; l++){
    int idx = tid + l * 256;
    int k = idx >> 5, c4 = (idx & 31) << 2;
    float4 w = *(const float4*)&W2[(size_t)k * D2_ + c4];
    union { __half2 h2[2]; float2 f2; } u;
    u.h2[0] = __floats2half2_rn(w.x, w.y);
    u.h2[1] = __floats2half2_rn(w.z, w.w);
    *(float2*)&Bsh[k][c4] = u.f2;
  }
  __syncthreads();
  int tr = tid >> 5, tc = tid & 31;
  float acc[4][4];
  #pragma unroll
  for(int i = 0; i < 4; i++)
    #pragma unroll
    for(int j = 0; j < 4; j++) acc[i][j] = 0.f;
  #pragma unroll 8
  for(int k = 0; k < 64; k++){
    float4 a4 = *(const float4*)&AsT[k][tr << 2];
    float2 b2v = *(const float2*)&Bsh[k][tc << 2];
    float av[4] = {a4.x, a4.y, a4.z, a4.w};
    #pragma unroll
    for(int i = 0; i < 4; i++){
      fma_mix_lo(acc[i][0], b2v.x, av[i]);
      fma_mix_hi(acc[i][1], b2v.x, av[i]);
      fma_mix_lo(acc[i][2], b2v.y, av[i]);
      fma_mix_hi(acc[i][3], b2v.y, av[i]);
    }
  }
  float al4[4], ar4[4];
  #pragma unroll
  for(int j = 0; j < 4; j++){
    al4[j] = al2[(tc << 2) + j];
    ar4[j] = ar2[(tc << 2) + j];
  }
  int col = tc << 2;
  int half = col >> 6, c64 = col & 63;
  #pragma unroll
  for(int i = 0; i < 4; i++){
    int row = n0 + (tr << 2) + i;
    bool ok = row < NN;
    if(ok){
      union { __half2 h2[2]; float2 f2; } u;
      u.h2[0] = __floats2half2_rn(acc[i][0], acc[i][1]);
      u.h2[1] = __floats2half2_rn(acc[i][2], acc[i][3]);
      *(float2*)&ft2h[((size_t)half * NN + row) * 64 + c64] = u.f2;
    }
    float e1 = acc[i][0]*al4[0] + acc[i][1]*al4[1] + acc[i][2]*al4[2] + acc[i][3]*al4[3];
    float e2 = acc[i][0]*ar4[0] + acc[i][1]*ar4[1] + acc[i][2]*ar4[2] + acc[i][3]*ar4[3];
    #pragma unroll
    for(int off = 1; off < 32; off <<= 1){
      e1 += __shfl_xor(e1, off, 64);
      e2 += __shfl_xor(e2, off, 64);
    }
    if(tc == 0 && ok){ el[row] = e1; er[row] = e2; }
  }
}

// ---------------- layer-2 attn+agg: 2 dn per half, A/B-interleaved; XCD-pinned d-half ----------------
__global__ __launch_bounds__(256) void l2_head(
    const int* __restrict__ cur, const int* __restrict__ ssrc,
    const float* __restrict__ el, const float* __restrict__ er,
    const __half* __restrict__ ft2h, const float* __restrict__ b2,
    float* __restrict__ h2v){
  __shared__ int2 pairs[4][2][2][32];
  int b = blockIdx.x;
  int xcd = b & 7, slot = b >> 3;
  int halfd = xcd >> 2;
  int blk = (xcd & 3) * 313 + slot;
  if(blk >= 1250) return;
  int wave = threadIdx.x >> 6, lane = threadIdx.x & 63;
  int half = lane >> 5, l32 = lane & 31;
  int eg = l32 >> 4, dg = l32 & 15;
  int dnA = blk * 16 + wave * 4 + half * 2;
  int dnB = dnA + 1;
  int degA = min(cur[dnA], CAP), degB = min(cur[dnB], CAP);
  int baseA = dnA << 7, baseB = dnB << 7;
  float4 accA = make_float4(0.f,0.f,0.f,0.f);
  float4 accB = make_float4(0.f,0.f,0.f,0.f);
  const char* fbase = (const char*)(ft2h + (size_t)halfd * NN * 64) + (dg << 3);
  float erA = er[dnA], erB = er[dnB];
  int2* wpA = pairs[wave][half][0];
  int2* wpB = pairs[wave][half][1];

  if(__any(degA > 32 || degB > 32)){
    #pragma unroll
    for(int which = 0; which < 2; which++){
      int base = which ? baseB : baseA;
      int deg  = which ? degB : degA;
      float er_d = which ? erB : erA;
      float4* accp = which ? &accB : &accA;
      int2* wp = which ? wpB : wpA;
      float sm = 0.f;
      for(int i = l32; i < deg; i += 32)
        sm += __expf(lrelu(el[ssrc[base + i]] + er_d));
      #pragma unroll
      for(int o = 1; o < 32; o <<= 1) sm += __shfl_xor(sm, o, 64);
      float inv = deg > 0 ? 1.f / sm : 0.f;
      for(int c = 0; c < deg; c += 32){
        int m = deg - c; if(m > 32) m = 32;
        if(l32 < m){
          int sn = ssrc[base + c + l32];
          wp[l32] = make_int2(__float_as_int(__expf(lrelu(el[sn] + er_d)) * inv), sn << 7);
        }
        for(int i = eg; i < m; i += 2){
          int2 pr = wp[i];
          float a_i = __int_as_float(pr.x);
          float2 raw = *(const float2*)(fbase + pr.y);
          fma_mix_lo(accp->x, raw.x, a_i); fma_mix_hi(accp->y, raw.x, a_i);
          fma_mix_lo(accp->z, raw.y, a_i); fma_mix_hi(accp->w, raw.y, a_i);
        }
      }
    }
  } else {
    int snA = 0, snB = 0;
    if(l32 < degA) snA = ssrc[baseA + l32];
    if(l32 < degB) snB = ssrc[baseB + l32];
    float pA = 0.f, pB = 0.f;
    if(l32 < degA) pA = __expf(lrelu(el[snA] + erA));
    if(l32 < degB) pB = __expf(lrelu(el[snB] + erB));
    float smA = pA, smB = pB;
    #pragma unroll
    for(int o = 1; o < 32; o <<= 1){
      smA += __shfl_xor(smA, o, 64);
      smB += __shfl_xor(smB, o, 64);
    }
    float invA = degA > 0 ? 1.f / smA : 0.f;
    float invB = degB > 0 ? 1.f / smB : 0.f;
    wpA[l32] = l32 < degA ? make_int2(__float_as_int(pA * invA), snA << 7)
                          : make_int2(0, 0);
    wpB[l32] = l32 < degB ? make_int2(__float_as_int(pB * invB), snB << 7)
                          : make_int2(0, 0);
    int maxd = max(degA, degB);
    int i = eg;
    for(; i + 2 < maxd; i += 4){
      int2 a0 = wpA[i], a1 = wpA[i + 2];
      int2 b0 = wpB[i], b1 = wpB[i + 2];
      float2 ra0 = *(const float2*)(fbase + a0.y);
      float2 rb0 = *(const float2*)(fbase + b0.y);
      float2 ra1 = *(const float2*)(fbase + a1.y);
      float2 rb1 = *(const float2*)(fbase + b1.y);
      float aa0 = __int_as_float(a0.x), aa1 = __int_as_float(a1.x);
      float ab0 = __int_as_float(b0.x), ab1 = __int_as_float(b1.x);
      fma_mix_lo(accA.x, ra0.x, aa0); fma_mix_hi(accA.y, ra0.x, aa0);
      fma_mix_lo(accA.z, ra0.y, aa0); fma_mix_hi(accA.w, ra0.y, aa0);
      fma_mix_lo(accB.x, rb0.x, ab0); fma_mix_hi(accB.y, rb0.x, ab0);
      fma_mix_lo(accB.z, rb0.y, ab0); fma_mix_hi(accB.w, rb0.y, ab0);
      fma_mix_lo(accA.x, ra1.x, aa1); fma_mix_hi(accA.y, ra1.x, aa1);
      fma_mix_lo(accA.z, ra1.y, aa1); fma_mix_hi(accA.w, ra1.y, aa1);
      fma_mix_lo(accB.x, rb1.x, ab1); fma_mix_hi(accB.y, rb1.x, ab1);
      fma_mix_lo(accB.z, rb1.y, ab1); fma_mix_hi(accB.w, rb1.y, ab1);
    }
    if(i < maxd){
      int2 a0 = wpA[i], b0 = wpB[i];
      float2 ra0 = *(const float2*)(fbase + a0.y);
      float2 rb0 = *(const float2*)(fbase + b0.y);
      float aa0 = __int_as_float(a0.x), ab0 = __int_as_float(b0.x);
      fma_mix_lo(accA.x, ra0.x, aa0); fma_mix_hi(accA.y, ra0.x, aa0);
      fma_mix_lo(accA.z, ra0.y, aa0); fma_mix_hi(accA.w, ra0.y, aa0);
      fma_mix_lo(accB.x, rb0.x, ab0); fma_mix_hi(accB.y, rb0.x, ab0);
      fma_mix_lo(accB.z, rb0.y, ab0); fma_mix_hi(accB.w, rb0.y, ab0);
    }
  }
  accA.x += __shfl_xor(accA.x, 16, 64); accB.x += __shfl_xor(accB.x, 16, 64);
  accA.y += __shfl_xor(accA.y, 16, 64); accB.y += __shfl_xor(accB.y, 16, 64);
  accA.z += __shfl_xor(accA.z, 16, 64); accB.z += __shfl_xor(accB.z, 16, 64);
  accA.w += __shfl_xor(accA.w, 16, 64); accB.w += __shfl_xor(accB.w, 16, 64);
  if(eg == 0){
    int doff = halfd * 64 + (dg << 2);
    const float* bp = &b2[doff];
    float b0 = bp[0], b1v = bp[1], b2v = bp[2], b3 = bp[3];
    float4 o;
    o.x = fmaxf(accA.x + b0, 0.f);
    o.y = fmaxf(accA.y + b1v, 0.f);
    o.z = fmaxf(accA.z + b2v, 0.f);
    o.w = fmaxf(accA.w + b3, 0.f);
    *(float4*)&h2v[(size_t)dnA * D2_ + doff] = o;
    o.x = fmaxf(accB.x + b0, 0.f);
    o.y = fmaxf(accB.y + b1v, 0.f);
    o.z = fmaxf(accB.z + b2v, 0.f);
    o.w = fmaxf(accB.w + b3, 0.f);
    *(float4*)&h2v[(size_t)dnB * D2_ + doff] = o;
  }
}

// ---------------- fused per-graph max + final MLP (graph_ids sorted) ----------------
__global__ __launch_bounds__(256) void readout(
    const float* __restrict__ h2v, const int* __restrict__ gid,
    const float* __restrict__ lw1, const float* __restrict__ lb1,
    const float* __restrict__ lw2, const float* __restrict__ lb2,
    float* __restrict__ out){
  __shared__ int sb[2];
  __shared__ float mx2[2][D2_];
  __shared__ float rv[D2_];
  __shared__ float t[D2_];
  int g = blockIdx.x, tid = threadIdx.x;
  int d = tid & 127, hh = tid >> 7;
  if(tid < 2){
    int tgt = g + tid;
    int lo = 0, hi = NN;
    while(lo < hi){ int mid = (lo + hi) >> 1; if(gid[mid] < tgt) lo = mid + 1; else hi = mid; }
    sb[tid] = lo;
  }
  __syncthreads();
  int gs = sb[0], ge = sb[1];
  float m0 = 0.f, m1 = 0.f, m2 = 0.f, m3 = 0.f;
  int n = gs + hh;
  for(; n + 6 < ge; n += 8){
    m0 = fmaxf(m0, h2v[(size_t)(n + 0) * D2_ + d]);
    m1 = fmaxf(m1, h2v[(size_t)(n + 2) * D2_ + d]);
    m2 = fmaxf(m2, h2v[(size_t)(n + 4) * D2_ + d]);
    m3 = fmaxf(m3, h2v[(size_t)(n + 6) * D2_ + d]);
  }
  for(; n < ge; n += 2) m0 = fmaxf(m0, h2v[(size_t)n * D2_ + d]);
  mx2[hh][d] = fmaxf(fmaxf(m0, m1), fmaxf(m2, m3));
  __syncthreads();
  if(tid < D2_) rv[d] = fmaxf(mx2[0][d], mx2[1][d]);
  __syncthreads();
  if(tid < D2_){
    float acc = lb1[d];
    #pragma unroll 8
    for(int k = 0; k < D2_; k++) acc += rv[k] * lw1[k * D2_ + d];
    acc = acc > 0.f ? acc : 0.f;
    t[d] = acc * lw2[d];
  }
  __syncthreads();
  for(int off = 64; off > 0; off >>= 1){
    if(tid < off) t[tid] += t[tid + off];
    __syncthreads();
  }
  if(tid == 0){
    float v = t[0] + lb2[0];
    out[g] = v > 0.f ? v : 0.f;
  }
}

extern "C" void kernel_launch(void* const* d_in, const int* in_sizes, int n_in,
                              void* d_out, int out_size, void* d_ws, size_t ws_size,
                              hipStream_t stream) {
  const float* feat = (const float*)d_in[0];
  const int*   src  = (const int*)d_in[1];
  const int*   dst  = (const int*)d_in[2];
  const int*   gid  = (const int*)d_in[3];
  const float* W1   = (const float*)d_in[4];
  const float* al1  = (const float*)d_in[5];
  const float* ar1  = (const float*)d_in[6];
  const float* b1   = (const float*)d_in[7];
  const float* W2   = (const float*)d_in[8];
  const float* al2  = (const float*)d_in[9];
  const float* ar2  = (const float*)d_in[10];
  const float* b2   = (const float*)d_in[11];
  const float* lw1  = (const float*)d_in[12];
  const float* lb1  = (const float*)d_in[13];
  const float* lw2  = (const float*)d_in[14];
  const float* lb2  = (const float*)d_in[15];
  float* out = (float*)d_out;

  float* ws = (float*)d_ws;
  size_t o = 0;
  _Float16* ft1h = (_Float16*)(ws + o); o += (size_t)NN * F1 / 2;    // 25.6MB
  __half* out1h = (__half*)(ws + o); o += (size_t)NN * F1 / 2;       // 25.6MB
  __half* ft2h = (__half*)(ws + o); o += (size_t)NN * D2_ / 2;       // 5.12MB
  float* h2v  = ws + o; o += (size_t)NN * D2_;                       // 10.24MB
  float* el1  = ws + o; o += (size_t)NN * H1_;
  float* er1  = ws + o; o += (size_t)NN * H1_;
  float* el2  = ws + o; o += NN;
  float* er2  = ws + o; o += NN;
  int* cur    = (int*)(ws + o); o += NN;
  int* ssrc   = (int*)(ws + o); o += (size_t)NN * CAP;               // 10.24MB
  _Float16* featH = (_Float16*)(ws + o); o += (size_t)NN * IN_ / 2;  // 2.56MB
  _Float16* W1T   = (_Float16*)(ws + o); o += (size_t)F1 * IN_ / 2;  // 80KB

  // prep: featH + W1T + zero cur
  prep<<<1290, 256, 0, stream>>>(feat, W1, featH, W1T, cur);
  // fused: bucket scatter (1250 blocks) + MFMA gemm1 (3130 blocks)
  fused1<<<1250 + H1_ * cdiv(NN, 64), 256, 0, stream>>>(
      src, dst, cur, ssrc, featH, W1T, al1, ar1, ft1h, el1, er1);
  // layer-1 attn+agg
  l1_head<<<8 * (1250 + 313), 256, 0, stream>>>(cur, ssrc, el1, er1,
                                                (const __half*)ft1h, b1, out1h);
  // layer 2 (head-sum fused into gemm2 A-load)
  gemm2<<<cdiv(NN, 32), 256, 0, stream>>>(out1h, W2, al2, ar2, ft2h, el2, er2);
  l2_head<<<8 * 313, 256, 0, stream>>>(cur, ssrc, el2, er2, ft2h, b2, h2v);
  // fused readout + MLP
  readout<<<GG, 256, 0, stream>>>(h2v, gid, lw1, lb1, lw2, lb2, out);
}

// Round 16
// 136.329 us; speedup vs baseline: 1.2122x; 1.0929x over previous
//
#include <hip/hip_runtime.h>
#include <hip/hip_fp16.h>

#define NN 20000
#define EE 320000
#define GG 50
#define IN_ 64
#define H1_ 10
#define D1_ 64
#define D2_ 128
#define F1 640   /* H1_*D1_ */
#define NEG 0.2f
#define CAP 128  /* bucket capacity per dst */

static inline int cdiv(long long a, int b){ return (int)((a + b - 1) / b); }

typedef _Float16 half8 __attribute__((ext_vector_type(8)));
typedef float f32x4 __attribute__((ext_vector_type(4)));

__device__ inline float lrelu(float x){ return x > 0.f ? x : NEG * x; }

__device__ inline void fma_mix_lo(float& acc, float packed, float a){
  asm("v_fma_mix_f32 %0, %1, %2, %0 op_sel_hi:[1,0,0]"
      : "+v"(acc) : "v"(packed), "v"(a));
}
__device__ inline void fma_mix_hi(float& acc, float packed, float a){
  asm("v_fma_mix_f32 %0, %1, %2, %0 op_sel:[1,0,0] op_sel_hi:[1,0,0]"
      : "+v"(acc) : "v"(packed), "v"(a));
}
// 8 halves (float4 raw) * a -> two float4 accumulators
__device__ inline void fma8(float4& c0, float4& c1, const float4& r, float a){
  fma_mix_lo(c0.x, r.x, a); fma_mix_hi(c0.y, r.x, a);
  fma_mix_lo(c0.z, r.y, a); fma_mix_hi(c0.w, r.y, a);
  fma_mix_lo(c1.x, r.z, a); fma_mix_hi(c1.y, r.z, a);
  fma_mix_lo(c1.z, r.w, a); fma_mix_hi(c1.w, r.w, a);
}

// ---------------- prep: feat->fp16, W1^T, W2^T fp16, zero cur ----------------
__global__ __launch_bounds__(256) void prep(
    const float* __restrict__ feat, const float* __restrict__ W1,
    const float* __restrict__ W2, _Float16* __restrict__ featH,
    _Float16* __restrict__ W1T, _Float16* __restrict__ W2T,
    int* __restrict__ cur){
  int b = blockIdx.x, t = threadIdx.x;
  if(b < 1250){
    int idx = b * 1024 + t * 4;
    float4 v = *(const float4*)&feat[idx];
    _Float16 h4[4] = {(_Float16)v.x, (_Float16)v.y, (_Float16)v.z, (_Float16)v.w};
    *(float2*)&featH[idx] = *(float2*)h4;
    if(t < 16) cur[b * 16 + t] = 0;
  } else if(b < 1290){
    int idx = (b - 1250) * 1024 + t * 4;
    int c = idx >> 6, k0 = idx & 63;
    _Float16 h4[4];
    #pragma unroll
    for(int j = 0; j < 4; j++) h4[j] = (_Float16)W1[(size_t)(k0 + j) * F1 + c];
    *(float2*)&W1T[idx] = *(float2*)h4;
  } else {
    int idx = (b - 1290) * 1024 + t * 4;  // 8 blocks: 8192 elems
    int c = idx >> 6, k0 = idx & 63;
    _Float16 h4[4];
    #pragma unroll
    for(int j = 0; j < 4; j++) h4[j] = (_Float16)W2[(size_t)(k0 + j) * D2_ + c];
    *(float2*)&W2T[idx] = *(float2*)h4;
  }
}

// ---------------- fused: bucket-scatter (blocks 0..1249) + MFMA GEMM1 ----------------
__global__ __launch_bounds__(256) void fused1(
    const int* __restrict__ src, const int* __restrict__ dst,
    int* __restrict__ cur, int* __restrict__ ssrc,
    const _Float16* __restrict__ featH, const _Float16* __restrict__ W1T,
    const float* __restrict__ al1, const float* __restrict__ ar1,
    _Float16* __restrict__ ft1h, float* __restrict__ elT, float* __restrict__ erT){
  __shared__ _Float16 sC[4][16][72];
  int b = blockIdx.x;
  if(b < 1250){
    int e = b * 256 + threadIdx.x;
    int d = dst[e];
    int pos = atomicAdd(&cur[d], 1);
    if(pos < CAP) ssrc[(d << 7) + pos] = src[e];
    return;
  }
  int b2 = b - 1250;
  int h = b2 % H1_;
  int n0 = (b2 / H1_) * 64;
  int tid = threadIdx.x, w = tid >> 6, l = tid & 63;
  int lr = l & 15, lk = l >> 4;
  int r0 = n0 + w * 16;
  int row = r0 + lr;
  half8 a0 = {}, a1 = {};
  if(row < NN){
    a0 = *(const half8*)&featH[row * 64 + lk * 8];
    a1 = *(const half8*)&featH[row * 64 + 32 + lk * 8];
  }
  f32x4 acc[4];
  #pragma unroll
  for(int c0 = 0; c0 < 4; c0++) acc[c0] = (f32x4){0.f, 0.f, 0.f, 0.f};
  #pragma unroll
  for(int c0 = 0; c0 < 4; c0++){
    int col = h * 64 + c0 * 16 + lr;
    half8 b0 = *(const half8*)&W1T[col * 64 + lk * 8];
    half8 b1 = *(const half8*)&W1T[col * 64 + 32 + lk * 8];
    acc[c0] = __builtin_amdgcn_mfma_f32_16x16x32_f16(a0, b0, acc[c0], 0, 0, 0);
    acc[c0] = __builtin_amdgcn_mfma_f32_16x16x32_f16(a1, b1, acc[c0], 0, 0, 0);
  }
  float elp[4] = {0.f,0.f,0.f,0.f}, erp[4] = {0.f,0.f,0.f,0.f};
  #pragma unroll
  for(int c0 = 0; c0 < 4; c0++){
    float al = al1[h * 64 + c0 * 16 + lr];
    float ar = ar1[h * 64 + c0 * 16 + lr];
    #pragma unroll
    for(int j = 0; j < 4; j++){
      elp[j] += acc[c0][j] * al;
      erp[j] += acc[c0][j] * ar;
    }
  }
  #pragma unroll
  for(int off = 1; off < 16; off <<= 1){
    #pragma unroll
    for(int j = 0; j < 4; j++){
      elp[j] += __shfl_xor(elp[j], off, 64);
      erp[j] += __shfl_xor(erp[j], off, 64);
    }
  }
  if(lr == 0){
    #pragma unroll
    for(int j = 0; j < 4; j++){
      int rj = r0 + lk * 4 + j;
      if(rj < NN){
        elT[(size_t)h * NN + rj] = elp[j];
        erT[(size_t)h * NN + rj] = erp[j];
      }
    }
  }
  #pragma unroll
  for(int c0 = 0; c0 < 4; c0++)
    #pragma unroll
    for(int j = 0; j < 4; j++)
      sC[w][lk * 4 + j][c0 * 16 + lr] = (_Float16)acc[c0][j];
  __syncthreads();
  #pragma unroll
  for(int it = 0; it < 2; it++){
    int idx = l + it * 64;
    int orow = idx >> 3, oc = (idx & 7) * 8;
    int grow = r0 + orow;
    if(grow < NN)
      *(float4*)&ft1h[((size_t)h * NN + grow) * 64 + oc] =
          *(const float4*)&sC[w][orow][oc];
  }
}

// ---------------- layer-1 attn+agg: 2 dn per 32-lane half; 4 eg x 8 dg x 8 dims ----------------
__global__ __launch_bounds__(256) void l1_head(
    const int* __restrict__ cur, const int* __restrict__ ssrc,
    const float* __restrict__ elT, const float* __restrict__ erT,
    const __half* __restrict__ ft1h, const float* __restrict__ b1,
    __half* __restrict__ out1h){
  __shared__ int2 pairs[4][2][2][32];
  int b = blockIdx.x;
  int xcd = b & 7, slot = b >> 3;
  int h, blk;
  if(slot < 1250){ h = xcd; blk = slot; }
  else {
    int s = slot - 1250; h = 8 + (xcd >> 2); blk = (xcd & 3) * 313 + s;
    if(blk >= 1250) return;
  }
  int wave = threadIdx.x >> 6, lane = threadIdx.x & 63;
  int half = lane >> 5, l32 = lane & 31;
  int eg = l32 >> 3, dg = l32 & 7;
  int dnA = blk * 16 + wave * 4 + half * 2;
  int dnB = dnA + 1;
  int degA = min(cur[dnA], CAP), degB = min(cur[dnB], CAP);
  int baseA = dnA << 7, baseB = dnB << 7;
  float4 accA0 = make_float4(0.f,0.f,0.f,0.f), accA1 = accA0;
  float4 accB0 = accA0, accB1 = accA0;
  const char* fbase = (const char*)(ft1h + (size_t)h * NN * 64) + (dg << 4);
  const float* elh = elT + (size_t)h * NN;
  float erA = erT[(size_t)h * NN + dnA];
  float erB = erT[(size_t)h * NN + dnB];
  int2* wpA = pairs[wave][half][0];
  int2* wpB = pairs[wave][half][1];

  if(__any(degA > 32 || degB > 32)){
    // chunked fallback (rare)
    #pragma unroll
    for(int which = 0; which < 2; which++){
      int base = which ? baseB : baseA;
      int deg  = which ? degB : degA;
      float er_h = which ? erB : erA;
      float4* p0 = which ? &accB0 : &accA0;
      float4* p1 = which ? &accB1 : &accA1;
      int2* wp = which ? wpB : wpA;
      float sm = 0.f;
      for(int i = l32; i < deg; i += 32)
        sm += __expf(lrelu(elh[ssrc[base + i]] + er_h));
      #pragma unroll
      for(int o = 1; o < 32; o <<= 1) sm += __shfl_xor(sm, o, 64);
      float inv = deg > 0 ? 1.f / sm : 0.f;
      for(int c = 0; c < deg; c += 32){
        int m = deg - c; if(m > 32) m = 32;
        if(l32 < m){
          int sn = ssrc[base + c + l32];
          wp[l32] = make_int2(__float_as_int(__expf(lrelu(elh[sn] + er_h)) * inv), sn << 7);
        }
        for(int i = eg; i < m; i += 4){
          int2 pr = wp[i];
          float4 raw = *(const float4*)(fbase + pr.y);
          fma8(*p0, *p1, raw, __int_as_float(pr.x));
        }
      }
    }
  } else {
    int snA = 0, snB = 0;
    if(l32 < degA) snA = ssrc[baseA + l32];
    if(l32 < degB) snB = ssrc[baseB + l32];
    float pA = 0.f, pB = 0.f;
    if(l32 < degA) pA = __expf(lrelu(elh[snA] + erA));
    if(l32 < degB) pB = __expf(lrelu(elh[snB] + erB));
    float smA = pA, smB = pB;
    #pragma unroll
    for(int o = 1; o < 32; o <<= 1){
      smA += __shfl_xor(smA, o, 64);
      smB += __shfl_xor(smB, o, 64);
    }
    float invA = degA > 0 ? 1.f / smA : 0.f;
    float invB = degB > 0 ? 1.f / smB : 0.f;
    wpA[l32] = l32 < degA ? make_int2(__float_as_int(pA * invA), snA << 7)
                          : make_int2(0, 0);
    wpB[l32] = l32 < degB ? make_int2(__float_as_int(pB * invB), snB << 7)
                          : make_int2(0, 0);
    int maxd = max(degA, degB);
    int i = eg;
    for(; i + 4 < maxd; i += 8){
      int2 a0 = wpA[i], a1 = wpA[i + 4];
      int2 b0 = wpB[i], b1 = wpB[i + 4];
      float4 ra0 = *(const float4*)(fbase + a0.y);
      float4 rb0 = *(const float4*)(fbase + b0.y);
      float4 ra1 = *(const float4*)(fbase + a1.y);
      float4 rb1 = *(const float4*)(fbase + b1.y);
      fma8(accA0, accA1, ra0, __int_as_float(a0.x));
      fma8(accB0, accB1, rb0, __int_as_float(b0.x));
      fma8(accA0, accA1, ra1, __int_as_float(a1.x));
      fma8(accB0, accB1, rb1, __int_as_float(b1.x));
    }
    if(i < maxd){
      int2 a0 = wpA[i], b0 = wpB[i];
      float4 ra0 = *(const float4*)(fbase + a0.y);
      float4 rb0 = *(const float4*)(fbase + b0.y);
      fma8(accA0, accA1, ra0, __int_as_float(a0.x));
      fma8(accB0, accB1, rb0, __int_as_float(b0.x));
    }
  }
  // reduce across the 4 edge-groups (xor 8, 16 within 32-lane half)
  #pragma unroll
  for(int off = 8; off <= 16; off <<= 1){
    accA0.x += __shfl_xor(accA0.x, off, 64); accA0.y += __shfl_xor(accA0.y, off, 64);
    accA0.z += __shfl_xor(accA0.z, off, 64); accA0.w += __shfl_xor(accA0.w, off, 64);
    accA1.x += __shfl_xor(accA1.x, off, 64); accA1.y += __shfl_xor(accA1.y, off, 64);
    accA1.z += __shfl_xor(accA1.z, off, 64); accA1.w += __shfl_xor(accA1.w, off, 64);
    accB0.x += __shfl_xor(accB0.x, off, 64); accB0.y += __shfl_xor(accB0.y, off, 64);
    accB0.z += __shfl_xor(accB0.z, off, 64); accB0.w += __shfl_xor(accB0.w, off, 64);
    accB1.x += __shfl_xor(accB1.x, off, 64); accB1.y += __shfl_xor(accB1.y, off, 64);
    accB1.z += __shfl_xor(accB1.z, off, 64); accB1.w += __shfl_xor(accB1.w, off, 64);
  }
  if(eg == 0){
    int d = dg << 3;
    const float* bp = &b1[h * 64 + d];
    union { __half2 h2[4]; float4 f4; } u;
    u.h2[0] = __floats2half2_rn(fmaxf(accA0.x + bp[0], 0.f), fmaxf(accA0.y + bp[1], 0.f));
    u.h2[1] = __floats2half2_rn(fmaxf(accA0.z + bp[2], 0.f), fmaxf(accA0.w + bp[3], 0.f));
    u.h2[2] = __floats2half2_rn(fmaxf(accA1.x + bp[4], 0.f), fmaxf(accA1.y + bp[5], 0.f));
    u.h2[3] = __floats2half2_rn(fmaxf(accA1.z + bp[6], 0.f), fmaxf(accA1.w + bp[7], 0.f));
    *(float4*)&out1h[(size_t)dnA * F1 + h * 64 + d] = u.f4;
    u.h2[0] = __floats2half2_rn(fmaxf(accB0.x + bp[0], 0.f), fmaxf(accB0.y + bp[1], 0.f));
    u.h2[1] = __floats2half2_rn(fmaxf(accB0.z + bp[2], 0.f), fmaxf(accB0.w + bp[3], 0.f));
    u.h2[2] = __floats2half2_rn(fmaxf(accB1.x + bp[4], 0.f), fmaxf(accB1.y + bp[5], 0.f));
    u.h2[3] = __floats2half2_rn(fmaxf(accB1.z + bp[6], 0.f), fmaxf(accB1.w + bp[7], 0.f));
    *(float4*)&out1h[(size_t)dnB * F1 + h * 64 + d] = u.f4;
  }
}

// ---------------- MFMA GEMM2: A = fp16 head-sum(out1h); B = W2T; fused el2/er2 ----------------
__global__ __launch_bounds__(256) void gemm2(
    const _Float16* __restrict__ out1h, const _Float16* __restrict__ W2T,
    const float* __restrict__ al2, const float* __restrict__ ar2,
    _Float16* __restrict__ ft2h, float* __restrict__ el, float* __restrict__ er){
  __shared__ _Float16 sC[4][16][136];
  int n0 = blockIdx.x * 64;
  int tid = threadIdx.x, w = tid >> 6, l = tid & 63;
  int lr = l & 15, lk = l >> 4;
  int r0 = n0 + w * 16;
  int row = r0 + lr;
  half8 a0 = {}, a1 = {};
  if(row < NN){
    const _Float16* rp = out1h + (size_t)row * F1;
    half8 s0 = *(const half8*)(rp + lk * 8);
    half8 s1 = *(const half8*)(rp + 32 + lk * 8);
    #pragma unroll
    for(int hh = 1; hh < H1_; hh++){
      s0 += *(const half8*)(rp + hh * 64 + lk * 8);
      s1 += *(const half8*)(rp + hh * 64 + 32 + lk * 8);
    }
    a0 = s0; a1 = s1;
  }
  f32x4 acc[8];
  #pragma unroll
  for(int c0 = 0; c0 < 8; c0++) acc[c0] = (f32x4){0.f, 0.f, 0.f, 0.f};
  #pragma unroll
  for(int c0 = 0; c0 < 8; c0++){
    int col = c0 * 16 + lr;
    half8 b0 = *(const half8*)&W2T[col * 64 + lk * 8];
    half8 b1 = *(const half8*)&W2T[col * 64 + 32 + lk * 8];
    acc[c0] = __builtin_amdgcn_mfma_f32_16x16x32_f16(a0, b0, acc[c0], 0, 0, 0);
    acc[c0] = __builtin_amdgcn_mfma_f32_16x16x32_f16(a1, b1, acc[c0], 0, 0, 0);
  }
  float elp[4] = {0.f,0.f,0.f,0.f}, erp[4] = {0.f,0.f,0.f,0.f};
  #pragma unroll
  for(int c0 = 0; c0 < 8; c0++){
    float al = al2[c0 * 16 + lr];
    float ar = ar2[c0 * 16 + lr];
    #pragma unroll
    for(int j = 0; j < 4; j++){
      elp[j] += acc[c0][j] * al;
      erp[j] += acc[c0][j] * ar;
    }
  }
  #pragma unroll
  for(int off = 1; off < 16; off <<= 1){
    #pragma unroll
    for(int j = 0; j < 4; j++){
      elp[j] += __shfl_xor(elp[j], off, 64);
      erp[j] += __shfl_xor(erp[j], off, 64);
    }
  }
  if(lr == 0){
    #pragma unroll
    for(int j = 0; j < 4; j++){
      int rj = r0 + lk * 4 + j;
      if(rj < NN){ el[rj] = elp[j]; er[rj] = erp[j]; }
    }
  }
  #pragma unroll
  for(int c0 = 0; c0 < 8; c0++)
    #pragma unroll
    for(int j = 0; j < 4; j++)
      sC[w][lk * 4 + j][c0 * 16 + lr] = (_Float16)acc[c0][j];
  __syncthreads();
  #pragma unroll
  for(int it = 0; it < 4; it++){
    int idx = l + it * 64;
    int orow = idx >> 4, oc = (idx & 15) * 8;
    int grow = r0 + orow;
    if(grow < NN)
      *(float4*)&ft2h[((size_t)(oc >> 6) * NN + grow) * 64 + (oc & 63)] =
          *(const float4*)&sC[w][orow][oc];
  }
}

// ---------------- layer-2 attn+agg: 2 dn per half; 4 eg x 8 dg x 8 dims ----------------
__global__ __launch_bounds__(256) void l2_head(
    const int* __restrict__ cur, const int* __restrict__ ssrc,
    const float* __restrict__ el, const float* __restrict__ er,
    const __half* __restrict__ ft2h, const float* __restrict__ b2,
    float* __restrict__ h2v){
  __shared__ int2 pairs[4][2][2][32];
  int b = blockIdx.x;
  int xcd = b & 7, slot = b >> 3;
  int halfd = xcd >> 2;
  int blk = (xcd & 3) * 313 + slot;
  if(blk >= 1250) return;
  int wave = threadIdx.x >> 6, lane = threadIdx.x & 63;
  int half = lane >> 5, l32 = lane & 31;
  int eg = l32 >> 3, dg = l32 & 7;
  int dnA = blk * 16 + wave * 4 + half * 2;
  int dnB = dnA + 1;
  int degA = min(cur[dnA], CAP), degB = min(cur[dnB], CAP);
  int baseA = dnA << 7, baseB = dnB << 7;
  float4 accA0 = make_float4(0.f,0.f,0.f,0.f), accA1 = accA0;
  float4 accB0 = accA0, accB1 = accA0;
  const char* fbase = (const char*)(ft2h + (size_t)halfd * NN * 64) + (dg << 4);
  float erA = er[dnA], erB = er[dnB];
  int2* wpA = pairs[wave][half][0];
  int2* wpB = pairs[wave][half][1];

  if(__any(degA > 32 || degB > 32)){
    #pragma unroll
    for(int which = 0; which < 2; which++){
      int base = which ? baseB : baseA;
      int deg  = which ? degB : degA;
      float er_d = which ? erB : erA;
      float4* p0 = which ? &accB0 : &accA0;
      float4* p1 = which ? &accB1 : &accA1;
      int2* wp = which ? wpB : wpA;
      float sm = 0.f;
      for(int i = l32; i < deg; i += 32)
        sm += __expf(lrelu(el[ssrc[base + i]] + er_d));
      #pragma unroll
      for(int o = 1; o < 32; o <<= 1) sm += __shfl_xor(sm, o, 64);
      float inv = deg > 0 ? 1.f / sm : 0.f;
      for(int c = 0; c < deg; c += 32){
        int m = deg - c; if(m > 32) m = 32;
        if(l32 < m){
          int sn = ssrc[base + c + l32];
          wp[l32] = make_int2(__float_as_int(__expf(lrelu(el[sn] + er_d)) * inv), sn << 7);
        }
        for(int i = eg; i < m; i += 4){
          int2 pr = wp[i];
          float4 raw = *(const float4*)(fbase + pr.y);
          fma8(*p0, *p1, raw, __int_as_float(pr.x));
        }
      }
    }
  } else {
    int snA = 0, snB = 0;
    if(l32 < degA) snA = ssrc[baseA + l32];
    if(l32 < degB) snB = ssrc[baseB + l32];
    float pA = 0.f, pB = 0.f;
    if(l32 < degA) pA = __expf(lrelu(el[snA] + erA));
    if(l32 < degB) pB = __expf(lrelu(el[snB] + erB));
    float smA = pA, smB = pB;
    #pragma unroll
    for(int o = 1; o < 32; o <<= 1){
      smA += __shfl_xor(smA, o, 64);
      smB += __shfl_xor(smB, o, 64);
    }
    float invA = degA > 0 ? 1.f / smA : 0.f;
    float invB = degB > 0 ? 1.f / smB : 0.f;
    wpA[l32] = l32 < degA ? make_int2(__float_as_int(pA * invA), snA << 7)
                          : make_int2(0, 0);
    wpB[l32] = l32 < degB ? make_int2(__float_as_int(pB * invB), snB << 7)
                          : make_int2(0, 0);
    int maxd = max(degA, degB);
    int i = eg;
    for(; i + 4 < maxd; i += 8){
      int2 a0 = wpA[i], a1 = wpA[i + 4];
      int2 b0 = wpB[i], b1 = wpB[i + 4];
      float4 ra0 = *(const float4*)(fbase + a0.y);
      float4 rb0 = *(const float4*)(fbase + b0.y);
      float4 ra1 = *(const float4*)(fbase + a1.y);
      float4 rb1 = *(const float4*)(fbase + b1.y);
      fma8(accA0, accA1, ra0, __int_as_float(a0.x));
      fma8(accB0, accB1, rb0, __int_as_float(b0.x));
      fma8(accA0, accA1, ra1, __int_as_float(a1.x));
      fma8(accB0, accB1, rb1, __int_as_float(b1.x));
    }
    if(i < maxd){
      int2 a0 = wpA[i], b0 = wpB[i];
      float4 ra0 = *(const float4*)(fbase + a0.y);
      float4 rb0 = *(const float4*)(fbase + b0.y);
      fma8(accA0, accA1, ra0, __int_as_float(a0.x));
      fma8(accB0, accB1, rb0, __int_as_float(b0.x));
    }
  }
  #pragma unroll
  for(int off = 8; off <= 16; off <<= 1){
    accA0.x += __shfl_xor(accA0.x, off, 64); accA0.y += __shfl_xor(accA0.y, off, 64);
    accA0.z += __shfl_xor(accA0.z, off, 64); accA0.w += __shfl_xor(accA0.w, off, 64);
    accA1.x += __shfl_xor(accA1.x, off, 64); accA1.y += __shfl_xor(accA1.y, off, 64);
    accA1.z += __shfl_xor(accA1.z, off, 64); accA1.w += __shfl_xor(accA1.w, off, 64);
    accB0.x += __shfl_xor(accB0.x, off, 64); accB0.y += __shfl_xor(accB0.y, off, 64);
    accB0.z += __shfl_xor(accB0.z, off, 64); accB0.w += __shfl_xor(accB0.w, off, 64);
    accB1.x += __shfl_xor(accB1.x, off, 64); accB1.y += __shfl_xor(accB1.y, off, 64);
    accB1.z += __shfl_xor(accB1.z, off, 64); accB1.w += __shfl_xor(accB1.w, off, 64);
  }
  if(eg == 0){
    int doff = halfd * 64 + (dg << 3);
    const float* bp = &b2[doff];
    float4 o;
    o.x = fmaxf(accA0.x + bp[0], 0.f);
    o.y = fmaxf(accA0.y + bp[1], 0.f);
    o.z = fmaxf(accA0.z + bp[2], 0.f);
    o.w = fmaxf(accA0.w + bp[3], 0.f);
    *(float4*)&h2v[(size_t)dnA * D2_ + doff] = o;
    o.x = fmaxf(accA1.x + bp[4], 0.f);
    o.y = fmaxf(accA1.y + bp[5], 0.f);
    o.z = fmaxf(accA1.z + bp[6], 0.f);
    o.w = fmaxf(accA1.w + bp[7], 0.f);
    *(float4*)&h2v[(size_t)dnA * D2_ + doff + 4] = o;
    o.x = fmaxf(accB0.x + bp[0], 0.f);
    o.y = fmaxf(accB0.y + bp[1], 0.f);
    o.z = fmaxf(accB0.z + bp[2], 0.f);
    o.w = fmaxf(accB0.w + bp[3], 0.f);
    *(float4*)&h2v[(size_t)dnB * D2_ + doff] = o;
    o.x = fmaxf(accB1.x + bp[4], 0.f);
    o.y = fmaxf(accB1.y + bp[5], 0.f);
    o.z = fmaxf(accB1.z + bp[6], 0.f);
    o.w = fmaxf(accB1.w + bp[7], 0.f);
    *(float4*)&h2v[(size_t)dnB * D2_ + doff + 4] = o;
  }
}

// ---------------- fused per-graph max + final MLP (graph_ids sorted) ----------------
__global__ __launch_bounds__(256) void readout(
    const float* __restrict__ h2v, const int* __restrict__ gid,
    const float* __restrict__ lw1, const float* __restrict__ lb1,
    const float* __restrict__ lw2, const float* __restrict__ lb2,
    float* __restrict__ out){
  __shared__ int sb[2];
  __shared__ float mx2[2][D2_];
  __shared__ float rv[D2_];
  __shared__ float t[D2_];
  int g = blockIdx.x, tid = threadIdx.x;
  int d = tid & 127, hh = tid >> 7;
  if(tid < 2){
    int tgt = g + tid;
    int lo = 0, hi = NN;
    while(lo < hi){ int mid = (lo + hi) >> 1; if(gid[mid] < tgt) lo = mid + 1; else hi = mid; }
    sb[tid] = lo;
  }
  __syncthreads();
  int gs = sb[0], ge = sb[1];
  float m0 = 0.f, m1 = 0.f, m2 = 0.f, m3 = 0.f;
  int n = gs + hh;
  for(; n + 6 < ge; n += 8){
    m0 = fmaxf(m0, h2v[(size_t)(n + 0) * D2_ + d]);
    m1 = fmaxf(m1, h2v[(size_t)(n + 2) * D2_ + d]);
    m2 = fmaxf(m2, h2v[(size_t)(n + 4) * D2_ + d]);
    m3 = fmaxf(m3, h2v[(size_t)(n + 6) * D2_ + d]);
  }
  for(; n < ge; n += 2) m0 = fmaxf(m0, h2v[(size_t)n * D2_ + d]);
  mx2[hh][d] = fmaxf(fmaxf(m0, m1), fmaxf(m2, m3));
  __syncthreads();
  if(tid < D2_) rv[d] = fmaxf(mx2[0][d], mx2[1][d]);
  __syncthreads();
  if(tid < D2_){
    float acc = lb1[d];
    #pragma unroll 8
    for(int k = 0; k < D2_; k++) acc += rv[k] * lw1[k * D2_ + d];
    acc = acc > 0.f ? acc : 0.f;
    t[d] = acc * lw2[d];
  }
  __syncthreads();
  for(int off = 64; off > 0; off >>= 1){
    if(tid < off) t[tid] += t[tid + off];
    __syncthreads();
  }
  if(tid == 0){
    float v = t[0] + lb2[0];
    out[g] = v > 0.f ? v : 0.f;
  }
}

extern "C" void kernel_launch(void* const* d_in, const int* in_sizes, int n_in,
                              void* d_out, int out_size, void* d_ws, size_t ws_size,
                              hipStream_t stream) {
  const float* feat = (const float*)d_in[0];
  const int*   src  = (const int*)d_in[1];
  const int*   dst  = (const int*)d_in[2];
  const int*   gid  = (const int*)d_in[3];
  const float* W1   = (const float*)d_in[4];
  const float* al1  = (const float*)d_in[5];
  const float* ar1  = (const float*)d_in[6];
  const float* b1   = (const float*)d_in[7];
  const float* W2   = (const float*)d_in[8];
  const float* al2  = (const float*)d_in[9];
  const float* ar2  = (const float*)d_in[10];
  const float* b2   = (const float*)d_in[11];
  const float* lw1  = (const float*)d_in[12];
  const float* lb1  = (const float*)d_in[13];
  const float* lw2  = (const float*)d_in[14];
  const float* lb2  = (const float*)d_in[15];
  float* out = (float*)d_out;

  float* ws = (float*)d_ws;
  size_t o = 0;
  _Float16* ft1h = (_Float16*)(ws + o); o += (size_t)NN * F1 / 2;    // 25.6MB
  _Float16* out1h = (_Float16*)(ws + o); o += (size_t)NN * F1 / 2;   // 25.6MB
  _Float16* ft2h = (_Float16*)(ws + o); o += (size_t)NN * D2_ / 2;   // 5.12MB
  float* h2v  = ws + o; o += (size_t)NN * D2_;                       // 10.24MB
  float* el1  = ws + o; o += (size_t)NN * H1_;
  float* er1  = ws + o; o += (size_t)NN * H1_;
  float* el2  = ws + o; o += NN;
  float* er2  = ws + o; o += NN;
  int* cur    = (int*)(ws + o); o += NN;
  int* ssrc   = (int*)(ws + o); o += (size_t)NN * CAP;               // 10.24MB
  _Float16* featH = (_Float16*)(ws + o); o += (size_t)NN * IN_ / 2;  // 2.56MB
  _Float16* W1T   = (_Float16*)(ws + o); o += (size_t)F1 * IN_ / 2;  // 80KB
  _Float16* W2T   = (_Float16*)(ws + o); o += (size_t)D2_ * IN_ / 2; // 16KB

  // prep: featH + W1T + W2T + zero cur
  prep<<<1298, 256, 0, stream>>>(feat, W1, W2, featH, W1T, W2T, cur);
  // fused: bucket scatter (1250 blocks) + MFMA gemm1 (3130 blocks)
  fused1<<<1250 + H1_ * cdiv(NN, 64), 256, 0, stream>>>(
      src, dst, cur, ssrc, featH, W1T, al1, ar1, ft1h, el1, er1);
  // layer-1 attn+agg
  l1_head<<<8 * (1250 + 313), 256, 0, stream>>>(cur, ssrc, el1, er1,
                                                (const __half*)ft1h, b1,
                                                (__half*)out1h);
  // layer 2: MFMA gemm2 (head-sum fused into A-load)
  gemm2<<<cdiv(NN, 64), 256, 0, stream>>>(out1h, W2T, al2, ar2, ft2h, el2, er2);
  l2_head<<<8 * 313, 256, 0, stream>>>(cur, ssrc, el2, er2,
                                       (const __half*)ft2h, b2, h2v);
  // fused readout + MLP
  readout<<<GG, 256, 0, stream>>>(h2v, gid, lw1, lb1, lw2, lb2, out);
}